// Round 4
// baseline (1488.907 us; speedup 1.0000x reference)
//
#include <hip/hip_runtime.h>

// Problem constants (match the reference).
#define BB 256
#define TT 2048
#define FF 64
#define UU 64
#define C3 192   // 3*U

__device__ __forceinline__ float fast_sigmoid(float x) {
    return __builtin_amdgcn_rcpf(1.0f + __expf(-x));
}
__device__ __forceinline__ float fast_tanh(float x) {
    return 1.0f - 2.0f * __builtin_amdgcn_rcpf(__expf(2.0f * x) + 1.0f);
}
__device__ __forceinline__ float shflx(float v, int m) {
    return __shfl_xor(v, m, 64);
}

#define REP16(M) M(0) M(1) M(2) M(3) M(4) M(5) M(6) M(7) \
                 M(8) M(9) M(10) M(11) M(12) M(13) M(14) M(15)

// ---------------------------------------------------------------------------
// One block per batch element, 4 waves, OUTPUT-split:
//   wave w owns units j in [16w, 16w+16); lane = sub*16+u handles unit
//   j = 16w+u over contraction rows [16*sub, 16*sub+16).
// Weights: 96 named VGPRs/lane (mask folded into U; mask in {0,2} -> exact).
// Per step: h and a come from LDS as float4 broadcasts (no readlanes),
// cross-sub reduce = shfl_xor(16/32) butterfly (allreduce), exchange = one
// 64-float h vector through double-buffered LDS, 1 barrier/step.
// Input rows staged 4 steps ahead into an 8-slot LDS ring by wave 0.
// amdgpu_waves_per_eu(1,1): we run exactly 1 wave/SIMD -> give the allocator
// the full register budget so nothing is demoted to AGPRs (rounds 1-3 bug).
// ---------------------------------------------------------------------------
__global__ void __launch_bounds__(256)
__attribute__((amdgpu_waves_per_eu(1, 1)))
gru_v4(const float* __restrict__ in, const float* __restrict__ kmat,
       const float* __restrict__ rk, const float* __restrict__ bias,
       const float* __restrict__ mask, const float* __restrict__ dw,
       const float* __restrict__ db, float* __restrict__ out) {
    __shared__ __align__(16) float hbuf[2][64];   // h double buffer
    __shared__ __align__(16) float abuf[8][64];   // input-row ring (t mod 8)

    const int b    = blockIdx.x;
    const int lane = threadIdx.x & 63;
    const int wv   = threadIdx.x >> 6;
    const int sub  = lane >> 4;        // contraction sub-block [0,4)
    const int u    = lane & 15;        // unit within wave
    const int j    = wv * 16 + u;      // this lane's output unit
    const int i0   = sub * 16;         // first contraction row

    // --- weights: rows i0..i0+15, column j, for {Uz,Ur,Uh,Kz,Kr,Kh}.
    // Recurrent-dropout mask folded into U (exact: mask in {0,2}).
    const float* mzp = mask;                         // [B][U]
    const float* mrp = mask + (size_t)BB * UU;
    const float* mhp = mask + (size_t)2 * BB * UU;
#define DECLW(K) float uz##K, ur##K, uh##K, kz##K, kr##K, kh##K;
    REP16(DECLW)
#define INITW(K) { const int i_ = i0 + (K); \
    uz##K = rk[i_ * C3 + j]        * mzp[(size_t)b * UU + i_]; \
    ur##K = rk[i_ * C3 + 64 + j]   * mrp[(size_t)b * UU + i_]; \
    uh##K = rk[i_ * C3 + 128 + j]  * mhp[(size_t)b * UU + i_]; \
    kz##K = kmat[i_ * C3 + j]; \
    kr##K = kmat[i_ * C3 + 64 + j]; \
    kh##K = kmat[i_ * C3 + 128 + j]; }
    REP16(INITW)

    // Per-unit biases (added once, after the butterfly reduce).
    const float bzj  = bias[j]       + bias[C3 + j];
    const float brj  = bias[64 + j]  + bias[C3 + 64 + j];
    const float bh0j = bias[128 + j];          // input-side h bias (outside r)
    const float bh1j = bias[C3 + 128 + j];     // recurrent h bias (inside r)

    const float* __restrict__ inb = in + (size_t)b * TT * FF + lane;

    // --- prologue: wave 0 stages input rows t=0,1 and zeroes h; holds t=2,3.
    float ga = 0.f, gb = 0.f;
    if (wv == 0) {
        const float t0v = inb[0];
        const float t1v = inb[(size_t)1 * FF];
        ga = inb[(size_t)2 * FF];
        gb = inb[(size_t)3 * FF];
        abuf[0][lane] = t0v;
        abuf[1][lane] = t1v;
        hbuf[0][lane] = 0.0f;
    }
    __syncthreads();

    float4 aA = *(const float4*)&abuf[0][i0];
    float4 aB = *(const float4*)&abuf[0][i0 + 4];
    float4 aC = *(const float4*)&abuf[0][i0 + 8];
    float4 aD = *(const float4*)&abuf[0][i0 + 12];

    float hown = 0.0f;   // h for unit j (replicated across subs)

#pragma unroll 1
    for (int e = 0; e < TT; ++e) {
        // h_e broadcast reads (written last step, ordered by the barrier).
        const float4 hA = *(const float4*)&hbuf[e & 1][i0];
        const float4 hB = *(const float4*)&hbuf[e & 1][i0 + 4];
        const float4 hC = *(const float4*)&hbuf[e & 1][i0 + 8];
        const float4 hD = *(const float4*)&hbuf[e & 1][i0 + 12];

        // a-part FMAs (independent of h -> execute under the h-read latency).
        float az = 0.f, ar = 0.f, axh = 0.f;
#define FMA_A(K, AV) { az = fmaf(AV, kz##K, az); ar = fmaf(AV, kr##K, ar); \
                       axh = fmaf(AV, kh##K, axh); }
        FMA_A(0, aA.x)  FMA_A(1, aA.y)  FMA_A(2, aA.z)  FMA_A(3, aA.w)
        FMA_A(4, aB.x)  FMA_A(5, aB.y)  FMA_A(6, aB.z)  FMA_A(7, aB.w)
        FMA_A(8, aC.x)  FMA_A(9, aC.y)  FMA_A(10, aC.z) FMA_A(11, aC.w)
        FMA_A(12, aD.x) FMA_A(13, aD.y) FMA_A(14, aD.z) FMA_A(15, aD.w)

        // h-part FMAs.
        float hz = 0.f, hr = 0.f, hah = 0.f;
#define FMA_H(K, HV) { hz = fmaf(HV, uz##K, hz); hr = fmaf(HV, ur##K, hr); \
                       hah = fmaf(HV, uh##K, hah); }
        FMA_H(0, hA.x)  FMA_H(1, hA.y)  FMA_H(2, hA.z)  FMA_H(3, hA.w)
        FMA_H(4, hB.x)  FMA_H(5, hB.y)  FMA_H(6, hB.z)  FMA_H(7, hB.w)
        FMA_H(8, hC.x)  FMA_H(9, hC.y)  FMA_H(10, hC.z) FMA_H(11, hC.w)
        FMA_H(12, hD.x) FMA_H(13, hD.y) FMA_H(14, hD.z) FMA_H(15, hD.w)

        // Butterfly allreduce over the 4 sub-blocks (xor 16, xor 32).
        float sz = az + hz, sr = ar + hr, sxh = axh, sah = hah;
        { float t0 = shflx(sz, 16), t1 = shflx(sr, 16),
                t2 = shflx(sxh, 16), t3 = shflx(sah, 16);
          sz += t0; sr += t1; sxh += t2; sah += t3; }
        { float t0 = shflx(sz, 32), t1 = shflx(sr, 32),
                t2 = shflx(sxh, 32), t3 = shflx(sah, 32);
          sz += t0; sr += t1; sxh += t2; sah += t3; }

        const float z  = fast_sigmoid(sz + bzj);
        const float r  = fast_sigmoid(sr + brj);
        const float hh = fast_tanh(fmaf(r, sah + bh1j, sxh + bh0j));
        hown = fmaf(z, hown - hh, hh);            // z*h + (1-z)*hh

        if (sub == 0) hbuf[(e + 1) & 1][j] = hown;
        if (wv == 0) {
            if (e + 2 < TT) abuf[(e + 2) & 7][lane] = ga;   // staged 2 steps ago
            ga = gb;
            if (e + 4 < TT) gb = inb[(size_t)(e + 4) * FF]; // prefetch 4 ahead
        }
        __syncthreads();

        if (e + 1 < TT) {
            aA = *(const float4*)&abuf[(e + 1) & 7][i0];
            aB = *(const float4*)&abuf[(e + 1) & 7][i0 + 4];
            aC = *(const float4*)&abuf[(e + 1) & 7][i0 + 8];
            aD = *(const float4*)&abuf[(e + 1) & 7][i0 + 12];
        }
    }

    // Dense head: out[b] = h_T @ dense_w + dense_b. hbuf[TT&1==0] holds h_T.
    if (wv == 0) {
        float p = hbuf[0][lane] * dw[lane];
#pragma unroll
        for (int o = 32; o > 0; o >>= 1) p += __shfl_down(p, o, 64);
        if (lane == 0) out[b] = p + db[0];
    }
}

// ---------------------------------------------------------------------------
extern "C" void kernel_launch(void* const* d_in, const int* in_sizes, int n_in,
                              void* d_out, int out_size, void* d_ws, size_t ws_size,
                              hipStream_t stream) {
    (void)in_sizes; (void)n_in; (void)d_ws; (void)ws_size; (void)out_size;
    const float* inputs = (const float*)d_in[0];
    const float* kmat   = (const float*)d_in[1];
    const float* rk     = (const float*)d_in[2];
    const float* bias   = (const float*)d_in[3];
    const float* dw     = (const float*)d_in[4];
    const float* db     = (const float*)d_in[5];
    const float* mask   = (const float*)d_in[6];
    float* out = (float*)d_out;

    gru_v4<<<BB, 256, 0, stream>>>(inputs, kmat, rk, bias, mask, dw, db, out);
}

// Round 5
// 1468.698 us; speedup vs baseline: 1.0138x; 1.0138x over previous
//
#include <hip/hip_runtime.h>

// Problem constants (match the reference).
#define BB 256
#define TT 2048
#define FF 64
#define UU 64
#define C3 192   // 3*U
#define CH 32    // input rows staged per chunk
#define NCH (TT / CH)

__device__ __forceinline__ float readlane_f(float v, int lane) {
    return __int_as_float(__builtin_amdgcn_readlane(__float_as_int(v), lane));
}
// sigmoid/tanh via v_exp/v_rcp; ~1e-6 error, threshold is 2e-2.
__device__ __forceinline__ float fast_sigmoid(float x) {
    return __builtin_amdgcn_rcpf(1.0f + __expf(-x));
}
__device__ __forceinline__ float fast_tanh(float x) {
    return 1.0f - 2.0f * __builtin_amdgcn_rcpf(__expf(2.0f * x) + 1.0f);
}

#define REP16(M) M(0) M(1) M(2) M(3) M(4) M(5) M(6) M(7) \
                 M(8) M(9) M(10) M(11) M(12) M(13) M(14) M(15)

// ---------------------------------------------------------------------------
// v5 = v3's cooperative contraction-split structure with the two measured
// pathologies fixed:
//  (a) NO global loads in the steady-state step body. Input rows are staged
//      into an LDS ring once per CH=32 steps: loads issued right AFTER the
//      barrier, ds_writes at the END of the body, so the __syncthreads
//      vmcnt(0) drain (which killed v3/v4: every barrier force-completed an
//      in-flight HBM load) overlaps ~400 cyc of work and fires 64x, not 2048x.
//  (b) amdgpu_waves_per_eu(1,1): we run exactly 1 wave/SIMD, so give the
//      allocator the whole register file -> no AGPR demotion of the 96
//      resident weights (v3: VGPR=80 with ~115 live -> accvgpr traffic).
// Pipelining: the input-projection FMAs for step t+1 (independent of h_t) sit
// between the partial-read issue and the partial-sum consumption, hiding the
// LDS read latency. Dropout mask folded into U (mask in {0,2} -> bit-exact).
// ---------------------------------------------------------------------------
__global__ void __launch_bounds__(256)
__attribute__((amdgpu_waves_per_eu(1, 1)))
gru_v5(const float* __restrict__ in, const float* __restrict__ kmat,
       const float* __restrict__ rk, const float* __restrict__ bias,
       const float* __restrict__ mask, const float* __restrict__ dw,
       const float* __restrict__ db, float* __restrict__ out) {
    __shared__ float ps[2][4][64][5];            // partials, stride-5: conflict-free
    __shared__ float abuf[2][CH][FF];            // input-row ring (2 chunks), 16 KB

    const int b    = blockIdx.x;
    const int lane = threadIdx.x & 63;
    const int wv   = threadIdx.x >> 6;
    const int i0   = wv << 4;                    // this wave's contraction-row base

    // Dropout masks (indexed by contraction row i).
    const float* mzp = mask;
    const float* mrp = mask + (size_t)BB * UU;
    const float* mhp = mask + (size_t)2 * BB * UU;

    // 96 named resident weights: rows i0..i0+15, column=lane, {Uz,Ur,Uh,Kz,Kr,Kh}.
#define DECLW(K) float uz##K, ur##K, uh##K, kz##K, kr##K, kh##K;
    REP16(DECLW)
#define INITW(K) { const int i_ = i0 + (K); \
    uz##K = rk[i_ * C3 + lane]        * mzp[(size_t)b * UU + i_]; \
    ur##K = rk[i_ * C3 + 64 + lane]   * mrp[(size_t)b * UU + i_]; \
    uh##K = rk[i_ * C3 + 128 + lane]  * mhp[(size_t)b * UU + i_]; \
    kz##K = kmat[i_ * C3 + lane]; \
    kr##K = kmat[i_ * C3 + 64 + lane]; \
    kh##K = kmat[i_ * C3 + 128 + lane]; }
    REP16(INITW)

    const float bzf = bias[lane]       + bias[C3 + lane];
    const float brf = bias[64 + lane]  + bias[C3 + 64 + lane];
    const float bh0 = bias[128 + lane];          // h input bias (outside r)
    const float bh1 = bias[C3 + 128 + lane];     // h recurrent bias (inside r)

    const float* __restrict__ inb = in + (size_t)b * TT * FF;

    // ---- prologue: stage chunk 0 (each wave: 8 rows), then prime a-pipeline.
    {
        const float* src = inb + (size_t)(wv * 8) * FF + lane;
        const float t0 = src[0 * FF], t1 = src[1 * FF], t2 = src[2 * FF],
                    t3 = src[3 * FF], t4 = src[4 * FF], t5 = src[5 * FF],
                    t6 = src[6 * FF], t7 = src[7 * FF];
        float* dst = &abuf[0][wv * 8][lane];
        dst[0 * FF] = t0; dst[1 * FF] = t1; dst[2 * FF] = t2; dst[3 * FF] = t3;
        dst[4 * FF] = t4; dst[5 * FF] = t5; dst[6 * FF] = t6; dst[7 * FF] = t7;
    }
    __syncthreads();

    // a-projection partials for step 0; a_cur = row 1.
    float az_p = 0.f, ar_p = 0.f, axh_p = 0.f;
    {
        const float a0 = abuf[0][0][lane];
#define FMA_A0(K) { const float s_ = readlane_f(a0, i0 + (K)); \
        az_p = fmaf(s_, kz##K, az_p); ar_p = fmaf(s_, kr##K, ar_p); \
        axh_p = fmaf(s_, kh##K, axh_p); }
        REP16(FMA_A0)
    }
    float a_cur = abuf[0][1][lane];
    float h = 0.0f;

#pragma unroll 1
    for (int t = 0; t < TT; ++t) {
        // ---- 1) h-part FMAs (h = h_t from previous iter), fold in a-parts.
        float pz = az_p, pr = ar_p, pxh = axh_p, pah = 0.f;
#define FMA_H(K) { const float hs_ = readlane_f(h, i0 + (K)); \
        pz  = fmaf(hs_, uz##K, pz); pr = fmaf(hs_, ur##K, pr); \
        pah = fmaf(hs_, uh##K, pah); }
        REP16(FMA_H)

        // ---- 2) publish partials, barrier.
        {
            float* wp = &ps[t & 1][wv][lane][0];
            wp[0] = pz; wp[1] = pr; wp[2] = pxh; wp[3] = pah;
        }
        __syncthreads();   // drains nothing heavy: no globals in flight here

        // ---- 3) chunk staging: issue loads NOW (top of post-barrier region),
        //         ds_write at the end of the body so vmcnt waits overlap work.
        const int  c        = t >> 5;
        const bool do_stage = ((t & (CH - 1)) == 0) && (c + 1 < NCH);
        float g0, g1, g2, g3, g4, g5, g6, g7;
        if (do_stage) {
            const float* src = inb + ((size_t)(c + 1) * CH + wv * 8) * FF + lane;
            g0 = src[0 * FF]; g1 = src[1 * FF]; g2 = src[2 * FF]; g3 = src[3 * FF];
            g4 = src[4 * FF]; g5 = src[5 * FF]; g6 = src[6 * FF]; g7 = src[7 * FF];
        }

        // ---- 4) issue the 16 partial reads early...
        const float* rp = &ps[t & 1][0][lane][0];
        const float q00 = rp[0],   q01 = rp[1],   q02 = rp[2],   q03 = rp[3];
        const float q10 = rp[320], q11 = rp[321], q12 = rp[322], q13 = rp[323];
        const float q20 = rp[640], q21 = rp[641], q22 = rp[642], q23 = rp[643];
        const float q30 = rp[960], q31 = rp[961], q32 = rp[962], q33 = rp[963];

        // ---- 5) ...and fill their latency with the a-projection for t+1
        //         (independent of h_t).
        float azn = 0.f, arn = 0.f, axhn = 0.f;
#define FMA_AN(K) { const float s_ = readlane_f(a_cur, i0 + (K)); \
        azn = fmaf(s_, kz##K, azn); arn = fmaf(s_, kr##K, arn); \
        axhn = fmaf(s_, kh##K, axhn); }
        REP16(FMA_AN)

        // prefetch input row t+2 from the LDS ring.
        const int rn = (t + 2 < TT) ? (t + 2) : (TT - 1);
        const float a_next = abuf[(rn >> 5) & 1][rn & (CH - 1)][lane];

        // ---- 6) reduce + activations + h update.
        const float sz  = ((bzf + q00) + (q10 + q20)) + q30;
        const float sr  = ((brf + q01) + (q11 + q21)) + q31;
        const float sxh = ((bh0 + q02) + (q12 + q22)) + q32;
        const float sah = ((bh1 + q03) + (q13 + q23)) + q33;
        const float z  = fast_sigmoid(sz);
        const float r  = fast_sigmoid(sr);
        const float hh = fast_tanh(fmaf(r, sah, sxh));
        h = fmaf(z, h - hh, hh);               // z*h + (1-z)*hh

        // ---- 7) retire staging: ds_writes (vmcnt waits have been covered).
        if (do_stage) {
            float* dst = &abuf[(c + 1) & 1][wv * 8][lane];
            dst[0 * FF] = g0; dst[1 * FF] = g1; dst[2 * FF] = g2; dst[3 * FF] = g3;
            dst[4 * FF] = g4; dst[5 * FF] = g5; dst[6 * FF] = g6; dst[7 * FF] = g7;
        }

        az_p = azn; ar_p = arn; axh_p = axhn;
        a_cur = a_next;
    }

    // Dense head: out[b] = h_T @ dense_w + dense_b (h replicated across waves).
    if (wv == 0) {
        float p = h * dw[lane];
#pragma unroll
        for (int o = 32; o > 0; o >>= 1) p += __shfl_down(p, o, 64);
        if (lane == 0) out[b] = p + db[0];
    }
}

// ---------------------------------------------------------------------------
extern "C" void kernel_launch(void* const* d_in, const int* in_sizes, int n_in,
                              void* d_out, int out_size, void* d_ws, size_t ws_size,
                              hipStream_t stream) {
    (void)in_sizes; (void)n_in; (void)d_ws; (void)ws_size; (void)out_size;
    const float* inputs = (const float*)d_in[0];
    const float* kmat   = (const float*)d_in[1];
    const float* rk     = (const float*)d_in[2];
    const float* bias   = (const float*)d_in[3];
    const float* dw     = (const float*)d_in[4];
    const float* db     = (const float*)d_in[5];
    const float* mask   = (const float*)d_in[6];
    float* out = (float*)d_out;

    gru_v5<<<BB, 256, 0, stream>>>(inputs, kmat, rk, bias, mask, dw, db, out);
}

// Round 6
// 1175.198 us; speedup vs baseline: 1.2669x; 1.2497x over previous
//
#include <hip/hip_runtime.h>

// Problem constants (match the reference).
#define BB 256
#define TT 2048
#define FF 64
#define UU 64
#define C3 192   // 3*U
#define CH 32    // input rows staged per chunk
#define NCH (TT / CH)

__device__ __forceinline__ float readlane_f(float v, int lane) {
    return __int_as_float(__builtin_amdgcn_readlane(__float_as_int(v), lane));
}
// sigmoid/tanh via v_exp/v_rcp; ~1e-6 error, threshold is 2e-2.
__device__ __forceinline__ float fast_sigmoid(float x) {
    return __builtin_amdgcn_rcpf(1.0f + __expf(-x));
}
__device__ __forceinline__ float fast_tanh(float x) {
    return 1.0f - 2.0f * __builtin_amdgcn_rcpf(__expf(2.0f * x) + 1.0f);
}

#define REP16(M) M(0) M(1) M(2) M(3) M(4) M(5) M(6) M(7) \
                 M(8) M(9) M(10) M(11) M(12) M(13) M(14) M(15)

// ---------------------------------------------------------------------------
// v6 = v3's winning skeleton (contraction-split over 4 waves, stride-5 LDS
// partials, redundant per-wave h update, ONE barrier/step, NO waves_per_eu
// attribute -- the common factor in the v4/v5 regressions) with exactly two
// deltas:
//  (1) chunked input staging: no global loads in the steady-state body, so
//      the per-barrier vmcnt(0) drain stops serializing an in-flight L3 load
//      every step (v3 paid this 2048x; now 64x, overlapped with ~350 cyc of
//      issued work between load-issue and ds_write retire).
//  (2) a-side broadcast from LDS: the input row is wave-uniform, so the
//      a-projection reads 4x ds_read_b128 (uniform addr = broadcast,
//      conflict-free) instead of 16 readlanes -- kills 16 VALU ops and their
//      VALU->SGPR->VALU hazard wait-states per step. h-side keeps readlane.
// Dropout mask folded into U weights (mask in {0,2} -> bit-exact).
// ---------------------------------------------------------------------------
__global__ void __launch_bounds__(256)
gru_v6(const float* __restrict__ in, const float* __restrict__ kmat,
       const float* __restrict__ rk, const float* __restrict__ bias,
       const float* __restrict__ mask, const float* __restrict__ dw,
       const float* __restrict__ db, float* __restrict__ out) {
    __shared__ float ps[2][4][64][5];            // partials, stride-5: conflict-free
    __shared__ __align__(16) float abuf[2][CH][FF];  // input-row ring, 16 KB

    const int b    = blockIdx.x;
    const int lane = threadIdx.x & 63;
    const int wv   = threadIdx.x >> 6;
    const int i0   = wv << 4;                    // this wave's contraction-row base

    // Dropout masks (indexed by contraction row i).
    const float* mzp = mask;
    const float* mrp = mask + (size_t)BB * UU;
    const float* mhp = mask + (size_t)2 * BB * UU;

    // 96 named resident weights: rows i0..i0+15, column=lane, {Uz,Ur,Uh,Kz,Kr,Kh}.
#define DECLW(K) float uz##K, ur##K, uh##K, kz##K, kr##K, kh##K;
    REP16(DECLW)
#define INITW(K) { const int i_ = i0 + (K); \
    uz##K = rk[i_ * C3 + lane]        * mzp[(size_t)b * UU + i_]; \
    ur##K = rk[i_ * C3 + 64 + lane]   * mrp[(size_t)b * UU + i_]; \
    uh##K = rk[i_ * C3 + 128 + lane]  * mhp[(size_t)b * UU + i_]; \
    kz##K = kmat[i_ * C3 + lane]; \
    kr##K = kmat[i_ * C3 + 64 + lane]; \
    kh##K = kmat[i_ * C3 + 128 + lane]; }
    REP16(INITW)

    const float bzf = bias[lane]       + bias[C3 + lane];
    const float brf = bias[64 + lane]  + bias[C3 + 64 + lane];
    const float bh0 = bias[128 + lane];          // h input bias (outside r)
    const float bh1 = bias[C3 + 128 + lane];     // h recurrent bias (inside r)

    const float* __restrict__ inb = in + (size_t)b * TT * FF;

    // ---- prologue: stage chunk 0 (each wave: 8 rows).
    {
        const float* src = inb + (size_t)(wv * 8) * FF + lane;
        const float t0 = src[0 * FF], t1 = src[1 * FF], t2 = src[2 * FF],
                    t3 = src[3 * FF], t4 = src[4 * FF], t5 = src[5 * FF],
                    t6 = src[6 * FF], t7 = src[7 * FF];
        float* dst = &abuf[0][wv * 8][lane];
        dst[0 * FF] = t0; dst[1 * FF] = t1; dst[2 * FF] = t2; dst[3 * FF] = t3;
        dst[4 * FF] = t4; dst[5 * FF] = t5; dst[6 * FF] = t6; dst[7 * FF] = t7;
    }
    __syncthreads();

    // a-projection FMAs: uniform-address broadcast reads, VGPR-only operands.
#define FMA_A(K, AV) { azn = fmaf(AV, kz##K, azn); arn = fmaf(AV, kr##K, arn); \
                       axhn = fmaf(AV, kh##K, axhn); }
#define FMA_A_ALL \
    FMA_A(0,  aA.x) FMA_A(1,  aA.y) FMA_A(2,  aA.z) FMA_A(3,  aA.w) \
    FMA_A(4,  aB.x) FMA_A(5,  aB.y) FMA_A(6,  aB.z) FMA_A(7,  aB.w) \
    FMA_A(8,  aC.x) FMA_A(9,  aC.y) FMA_A(10, aC.z) FMA_A(11, aC.w) \
    FMA_A(12, aD.x) FMA_A(13, aD.y) FMA_A(14, aD.z) FMA_A(15, aD.w)

    // ---- a-proj partials for step 0.
    float az_p, ar_p, axh_p;
    {
        const float* ab = &abuf[0][0][i0];
        const float4 aA = *(const float4*)(ab);
        const float4 aB = *(const float4*)(ab + 4);
        const float4 aC = *(const float4*)(ab + 8);
        const float4 aD = *(const float4*)(ab + 12);
        float azn = 0.f, arn = 0.f, axhn = 0.f;
        FMA_A_ALL
        az_p = azn; ar_p = arn; axh_p = axhn;
    }

    float h = 0.0f;

#pragma unroll 1
    for (int t = 0; t < TT; ++t) {
        // ---- 1) h-part FMAs (h = h_t), seeded with the a-projection partials.
        float pz = az_p, pr = ar_p, pxh = axh_p, pah = 0.f;
#define FMA_H(K) { const float hs_ = readlane_f(h, i0 + (K)); \
        pz  = fmaf(hs_, uz##K, pz); pr = fmaf(hs_, ur##K, pr); \
        pah = fmaf(hs_, uh##K, pah); }
        REP16(FMA_H)

        // ---- 2) publish partials, barrier (no globals in flight here).
        {
            float* wp = &ps[t & 1][wv][lane][0];
            wp[0] = pz; wp[1] = pr; wp[2] = pxh; wp[3] = pah;
        }
        __syncthreads();

        // ---- 3) chunk staging: issue loads at the earliest post-barrier
        //         point; ds_write at the END of the body (vmcnt wait overlaps
        //         everything in between).
        const int  c        = t >> 5;
        const bool do_stage = ((t & (CH - 1)) == 0) && (c + 1 < NCH);
        float g0, g1, g2, g3, g4, g5, g6, g7;
        if (do_stage) {
            const float* src = inb + ((size_t)(c + 1) * CH + wv * 8) * FF + lane;
            g0 = src[0 * FF]; g1 = src[1 * FF]; g2 = src[2 * FF]; g3 = src[3 * FF];
            g4 = src[4 * FF]; g5 = src[5 * FF]; g6 = src[6 * FF]; g7 = src[7 * FF];
        }

        // ---- 4) a-broadcast reads for step t+1 (issued FIRST so consuming
        //         them early doesn't force the partial reads to complete).
        const int rn = (t + 1 < TT) ? (t + 1) : (TT - 1);
        const float* ab = &abuf[(rn >> 5) & 1][rn & (CH - 1)][i0];
        const float4 aA = *(const float4*)(ab);
        const float4 aB = *(const float4*)(ab + 4);
        const float4 aC = *(const float4*)(ab + 8);
        const float4 aD = *(const float4*)(ab + 12);

        // ---- 5) issue the 16 partial reads...
        const float* rp = &ps[t & 1][0][lane][0];
        const float q00 = rp[0],   q01 = rp[1],   q02 = rp[2],   q03 = rp[3];
        const float q10 = rp[320], q11 = rp[321], q12 = rp[322], q13 = rp[323];
        const float q20 = rp[640], q21 = rp[641], q22 = rp[642], q23 = rp[643];
        const float q30 = rp[960], q31 = rp[961], q32 = rp[962], q33 = rp[963];

        // ---- 6) ...and fill their latency with the a-projection for t+1.
        float azn = 0.f, arn = 0.f, axhn = 0.f;
        FMA_A_ALL

        // ---- 7) reduce + activations + h update.
        const float sz  = ((bzf + q00) + (q10 + q20)) + q30;
        const float sr  = ((brf + q01) + (q11 + q21)) + q31;
        const float sxh = ((bh0 + q02) + (q12 + q22)) + q32;
        const float sah = ((bh1 + q03) + (q13 + q23)) + q33;
        const float z  = fast_sigmoid(sz);
        const float r  = fast_sigmoid(sr);
        const float hh = fast_tanh(fmaf(r, sah, sxh));
        h = fmaf(z, h - hh, hh);               // z*h + (1-z)*hh

        // ---- 8) retire staging: ds_writes (vmcnt waits covered by 4-7).
        if (do_stage) {
            float* dst = &abuf[(c + 1) & 1][wv * 8][lane];
            dst[0 * FF] = g0; dst[1 * FF] = g1; dst[2 * FF] = g2; dst[3 * FF] = g3;
            dst[4 * FF] = g4; dst[5 * FF] = g5; dst[6 * FF] = g6; dst[7 * FF] = g7;
        }

        az_p = azn; ar_p = arn; axh_p = axhn;
    }

    // Dense head: out[b] = h_T @ dense_w + dense_b (h replicated across waves).
    if (wv == 0) {
        float p = h * dw[lane];
#pragma unroll
        for (int o = 32; o > 0; o >>= 1) p += __shfl_down(p, o, 64);
        if (lane == 0) out[b] = p + db[0];
    }
}

// ---------------------------------------------------------------------------
extern "C" void kernel_launch(void* const* d_in, const int* in_sizes, int n_in,
                              void* d_out, int out_size, void* d_ws, size_t ws_size,
                              hipStream_t stream) {
    (void)in_sizes; (void)n_in; (void)d_ws; (void)ws_size; (void)out_size;
    const float* inputs = (const float*)d_in[0];
    const float* kmat   = (const float*)d_in[1];
    const float* rk     = (const float*)d_in[2];
    const float* bias   = (const float*)d_in[3];
    const float* dw     = (const float*)d_in[4];
    const float* db     = (const float*)d_in[5];
    const float* mask   = (const float*)d_in[6];
    float* out = (float*)d_out;

    gru_v6<<<BB, 256, 0, stream>>>(inputs, kmat, rk, bias, mask, dw, db, out);
}

// Round 7
// 1062.139 us; speedup vs baseline: 1.4018x; 1.1064x over previous
//
#include <hip/hip_runtime.h>

// Problem constants (match the reference).
#define BB 256
#define TT 2048
#define FF 64
#define UU 64
#define C3 192   // 3*U
#define CH 32    // input rows staged per chunk
#define NCH (TT / CH)

// sigmoid/tanh via v_exp/v_rcp; ~1e-6 error, threshold is 2e-2.
__device__ __forceinline__ float fast_sigmoid(float x) {
    return __builtin_amdgcn_rcpf(1.0f + __expf(-x));
}
__device__ __forceinline__ float fast_tanh(float x) {
    return 1.0f - 2.0f * __builtin_amdgcn_rcpf(__expf(2.0f * x) + 1.0f);
}
__device__ __forceinline__ float shflx(float v, int m) { return __shfl_xor(v, m, 64); }

#define REP16(M) M(0) M(1) M(2) M(3) M(4) M(5) M(6) M(7) \
                 M(8) M(9) M(10) M(11) M(12) M(13) M(14) M(15)

// ---------------------------------------------------------------------------
// v7: LDS-throughput-lean structure (v4 geometry, de-poisoned).
//   One block per batch, 4 waves. Wave w owns units j in [16w,16w+16);
//   lane = sub*16+u covers contraction rows [16sub,16sub+16) of unit j.
//   - cross-sub reduce: shfl_xor(16/32) butterfly -- NO LDS partials array
//     (v3/v6 spent ~470+ cyc/step of per-CU LDS pipe on scalar partial
//     reads/writes; here the whole exchange is 8 shuffles).
//   - h exchange: one 64-float vector; 16-lane b32 write + 4 broadcast
//     b128 reads per wave (same-address broadcast = conflict-free).
//   - inputs: LDS ring staged by ALL waves once per CH=32 steps (loads
//     issued right after a barrier, ds_writes at body end -> barrier never
//     drains a fresh global load); a-frags prefetched 1 step ahead.
//   - NO amdgpu_waves_per_eu (common factor of the v4/v5 regressions).
//   Dropout mask folded into U weights (mask in {0,2} -> bit-exact).
// ---------------------------------------------------------------------------
__global__ void __launch_bounds__(256, 1)
gru_v7(const float* __restrict__ in, const float* __restrict__ kmat,
       const float* __restrict__ rk, const float* __restrict__ bias,
       const float* __restrict__ mask, const float* __restrict__ dw,
       const float* __restrict__ db, float* __restrict__ out) {
    __shared__ __align__(16) float hb[2][64];        // h double buffer
    __shared__ __align__(16) float ab[2][CH][FF];    // input ring, 16 KB

    const int b    = blockIdx.x;
    const int lane = threadIdx.x & 63;
    const int wv   = threadIdx.x >> 6;
    const int sub  = lane >> 4;          // contraction sub-block [0,4)
    const int u    = lane & 15;          // unit within wave
    const int j    = (wv << 4) + u;      // this lane's output unit
    const int i0   = sub << 4;           // first contraction row

    // Weights: rows i0..i0+15, column j; dropout mask folded into U.
    const float* mzp = mask;
    const float* mrp = mask + (size_t)BB * UU;
    const float* mhp = mask + (size_t)2 * BB * UU;
#define DECLW(K) float uz##K, ur##K, uh##K, kz##K, kr##K, kh##K;
    REP16(DECLW)
#define INITW(K) { const int i_ = i0 + (K); \
    uz##K = rk[i_ * C3 + j]       * mzp[(size_t)b * UU + i_]; \
    ur##K = rk[i_ * C3 + 64 + j]  * mrp[(size_t)b * UU + i_]; \
    uh##K = rk[i_ * C3 + 128 + j] * mhp[(size_t)b * UU + i_]; \
    kz##K = kmat[i_ * C3 + j]; \
    kr##K = kmat[i_ * C3 + 64 + j]; \
    kh##K = kmat[i_ * C3 + 128 + j]; }
    REP16(INITW)

    // Per-unit biases, added once after the butterfly.
    const float bzj  = bias[j]       + bias[C3 + j];
    const float brj  = bias[64 + j]  + bias[C3 + 64 + j];
    const float bh0j = bias[128 + j];        // h input bias (outside r)
    const float bh1j = bias[C3 + 128 + j];   // h recurrent bias (inside r)

    const float* __restrict__ inb = in + (size_t)b * TT * FF;

    // ---- prologue: stage chunk 0 (each wave 8 rows); wave0 zeroes h.
    {
        const float* src = inb + (size_t)(wv * 8) * FF + lane;
        const float t0 = src[0 * FF], t1 = src[1 * FF], t2 = src[2 * FF],
                    t3 = src[3 * FF], t4 = src[4 * FF], t5 = src[5 * FF],
                    t6 = src[6 * FF], t7 = src[7 * FF];
        float* dst = &ab[0][wv * 8][lane];
        dst[0 * FF] = t0; dst[1 * FF] = t1; dst[2 * FF] = t2; dst[3 * FF] = t3;
        dst[4 * FF] = t4; dst[5 * FF] = t5; dst[6 * FF] = t6; dst[7 * FF] = t7;
    }
    if (wv == 0) hb[0][lane] = 0.0f;
    __syncthreads();

    // a-fragments for step 0 (held in registers, refreshed 1 step ahead).
    float4 aA = *(const float4*)&ab[0][0][i0];
    float4 aB = *(const float4*)&ab[0][0][i0 + 4];
    float4 aC = *(const float4*)&ab[0][0][i0 + 8];
    float4 aD = *(const float4*)&ab[0][0][i0 + 12];

    float hown = 0.0f;   // h for unit j (replicated across subs)

#pragma unroll 1
    for (int e = 0; e < TT; ++e) {
        const int  c  = e >> 5;
        const bool st = ((e & 31) == 0) && (c + 1 < NCH);

        // staging loads: issued at the earliest post-barrier point.
        float g0, g1, g2, g3, g4, g5, g6, g7;
        if (st) {
            const float* src = inb + ((size_t)(c + 1) * CH + wv * 8) * FF + lane;
            g0 = src[0 * FF]; g1 = src[1 * FF]; g2 = src[2 * FF]; g3 = src[3 * FF];
            g4 = src[4 * FF]; g5 = src[5 * FF]; g6 = src[6 * FF]; g7 = src[7 * FF];
        }

        // h_e broadcast reads (chain head; latency filled by a-FMAs below).
        const float4 hA = *(const float4*)&hb[e & 1][i0];
        const float4 hB = *(const float4*)&hb[e & 1][i0 + 4];
        const float4 hC = *(const float4*)&hb[e & 1][i0 + 8];
        const float4 hD = *(const float4*)&hb[e & 1][i0 + 12];

        // a-part FMAs (independent of h).
        float az = 0.f, ar = 0.f, axh = 0.f;
#define FMA_A(K, AV) { az = fmaf(AV, kz##K, az); ar = fmaf(AV, kr##K, ar); \
                       axh = fmaf(AV, kh##K, axh); }
        FMA_A(0,  aA.x) FMA_A(1,  aA.y) FMA_A(2,  aA.z) FMA_A(3,  aA.w)
        FMA_A(4,  aB.x) FMA_A(5,  aB.y) FMA_A(6,  aB.z) FMA_A(7,  aB.w)
        FMA_A(8,  aC.x) FMA_A(9,  aC.y) FMA_A(10, aC.z) FMA_A(11, aC.w)
        FMA_A(12, aD.x) FMA_A(13, aD.y) FMA_A(14, aD.z) FMA_A(15, aD.w)

        // h-part FMAs.
        float hz = 0.f, hr = 0.f, hah = 0.f;
#define FMA_H(K, HV) { hz = fmaf(HV, uz##K, hz); hr = fmaf(HV, ur##K, hr); \
                       hah = fmaf(HV, uh##K, hah); }
        FMA_H(0,  hA.x) FMA_H(1,  hA.y) FMA_H(2,  hA.z) FMA_H(3,  hA.w)
        FMA_H(4,  hB.x) FMA_H(5,  hB.y) FMA_H(6,  hB.z) FMA_H(7,  hB.w)
        FMA_H(8,  hC.x) FMA_H(9,  hC.y) FMA_H(10, hC.z) FMA_H(11, hC.w)
        FMA_H(12, hD.x) FMA_H(13, hD.y) FMA_H(14, hD.z) FMA_H(15, hD.w)

        // Butterfly allreduce across the 4 sub-blocks (xor 16, then 32).
        float sz = az + hz, sr = ar + hr, sxh = axh, sah = hah;
        { const float t0 = shflx(sz, 16), t1 = shflx(sr, 16),
                      t2 = shflx(sxh, 16), t3 = shflx(sah, 16);
          sz += t0; sr += t1; sxh += t2; sah += t3; }
        { const float t0 = shflx(sz, 32), t1 = shflx(sr, 32),
                      t2 = shflx(sxh, 32), t3 = shflx(sah, 32);
          sz += t0; sr += t1; sxh += t2; sah += t3; }

        const float z  = fast_sigmoid(sz + bzj);
        const float r  = fast_sigmoid(sr + brj);
        const float hh = fast_tanh(fmaf(r, sah + bh1j, sxh + bh0j));
        hown = fmaf(z, hown - hh, hh);          // z*h + (1-z)*hh

        if (sub == 0) hb[(e + 1) & 1][j] = hown;

        // prefetch a-fragments for step e+1 from the ring.
        const int rn = (e + 1 < TT) ? (e + 1) : (TT - 1);
        const float* ap = &ab[(rn >> 5) & 1][rn & (CH - 1)][i0];
        aA = *(const float4*)(ap);
        aB = *(const float4*)(ap + 4);
        aC = *(const float4*)(ap + 8);
        aD = *(const float4*)(ap + 12);

        // retire staging: ds_writes (vmcnt wait overlapped the whole body).
        if (st) {
            float* dst = &ab[(c + 1) & 1][wv * 8][lane];
            dst[0 * FF] = g0; dst[1 * FF] = g1; dst[2 * FF] = g2; dst[3 * FF] = g3;
            dst[4 * FF] = g4; dst[5 * FF] = g5; dst[6 * FF] = g6; dst[7 * FF] = g7;
        }

        __syncthreads();
    }

    // Dense head: out[b] = h_T @ dense_w + dense_b (h_T sits in hb[0]).
    if (wv == 0) {
        float p = hb[0][lane] * dw[lane];
#pragma unroll
        for (int o = 32; o > 0; o >>= 1) p += __shfl_down(p, o, 64);
        if (lane == 0) out[b] = p + db[0];
    }
}

// ---------------------------------------------------------------------------
extern "C" void kernel_launch(void* const* d_in, const int* in_sizes, int n_in,
                              void* d_out, int out_size, void* d_ws, size_t ws_size,
                              hipStream_t stream) {
    (void)in_sizes; (void)n_in; (void)d_ws; (void)ws_size; (void)out_size;
    const float* inputs = (const float*)d_in[0];
    const float* kmat   = (const float*)d_in[1];
    const float* rk     = (const float*)d_in[2];
    const float* bias   = (const float*)d_in[3];
    const float* dw     = (const float*)d_in[4];
    const float* db     = (const float*)d_in[5];
    const float* mask   = (const float*)d_in[6];
    float* out = (float*)d_out;

    gru_v7<<<BB, 256, 0, stream>>>(inputs, kmat, rk, bias, mask, dw, db, out);
}